// Round 11
// baseline (578.513 us; speedup 1.0000x reference)
//
#include <hip/hip_runtime.h>
#include <hip/hip_cooperative_groups.h>
#include <cstddef>

namespace cg = cooperative_groups;

typedef __attribute__((ext_vector_type(8))) short bf16x8;
typedef __attribute__((ext_vector_type(4))) float f32x4;

__device__ __forceinline__ float lrelu(float x) { return x >= 0.f ? x : 0.2f * x; }
// RNE float -> bf16
__device__ __forceinline__ unsigned short f2bf(float x) {
    unsigned u = __float_as_uint(x);
    u += 0x7FFFu + ((u >> 16) & 1u);
    return (unsigned short)(u >> 16);
}

// ======================= gemm phase (device function) =======================
// units U in [0,1280): n-tile = U/128 (64 n), m-tile = U%128 (64 m). 256 threads/unit,
// two units per 512-thread block (su = t>>8). No LDS, no barriers.
template <int K, int MODE>
__device__ __forceinline__ void gemm_phase(
    int blk, int nvb, int t,
    const float* __restrict__ Af32, const float* __restrict__ aggP,
    const float* __restrict__ Zpart, const unsigned short* __restrict__ WTg,
    const float* __restrict__ bias, const float* __restrict__ avec,
    float* __restrict__ srcp, float* __restrict__ dstp,
    unsigned short* __restrict__ hTf)
{
    const int su = t >> 8, tl = t & 255;
    const int w = tl >> 6, lane = tl & 63;
    const int colg = lane & 15, rquad = lane >> 4;
    const int koff = rquad * 8;
    for (int U = blk * 2 + su; U < 1280; U += nvb * 2) {
        const int n0 = (U >> 7) * 64, m0 = (U & 127) * 64;
        const int m = m0 + w * 16 + colg;
        float zi = 0.f;
        if (MODE == 1) zi = 1.f / (Zpart[m] + Zpart[8192 + m]);
        f32x4 acc[4] = {};
#pragma unroll
        for (int kk = 0; kk < K; kk += 32) {
            bf16x8 af;
            size_t off = (size_t)m * K + kk + koff;
            if (MODE == 1) {
                float4 a0 = *(const float4*)&aggP[off];
                float4 a1 = *(const float4*)&aggP[off + 4];
                float4 b0 = *(const float4*)&aggP[off + 1048576];
                float4 b1 = *(const float4*)&aggP[off + 1048576 + 4];
                af[0] = (short)f2bf(lrelu((a0.x + b0.x) * zi));
                af[1] = (short)f2bf(lrelu((a0.y + b0.y) * zi));
                af[2] = (short)f2bf(lrelu((a0.z + b0.z) * zi));
                af[3] = (short)f2bf(lrelu((a0.w + b0.w) * zi));
                af[4] = (short)f2bf(lrelu((a1.x + b1.x) * zi));
                af[5] = (short)f2bf(lrelu((a1.y + b1.y) * zi));
                af[6] = (short)f2bf(lrelu((a1.z + b1.z) * zi));
                af[7] = (short)f2bf(lrelu((a1.w + b1.w) * zi));
            } else {
                float4 q0 = *(const float4*)&Af32[off];
                float4 q1 = *(const float4*)&Af32[off + 4];
                af[0] = (short)f2bf(q0.x); af[1] = (short)f2bf(q0.y);
                af[2] = (short)f2bf(q0.z); af[3] = (short)f2bf(q0.w);
                af[4] = (short)f2bf(q1.x); af[5] = (short)f2bf(q1.y);
                af[6] = (short)f2bf(q1.z); af[7] = (short)f2bf(q1.w);
            }
#pragma unroll
            for (int ct = 0; ct < 4; ++ct) {
                bf16x8 bfv = *(const bf16x8*)&WTg[(size_t)(n0 + ct * 16 + colg) * K + kk + koff];
                acc[ct] = __builtin_amdgcn_mfma_f32_16x16x32_bf16(af, bfv, acc[ct], 0, 0, 0);
            }
        }
        // epilogue: bias, src/dst partial dots (shfl over colg), hTf fragment stores
        const int r = n0 >> 7, chalf = n0 & 127;
        const int b = m0 >> 8, jb = m0 & 255;
        float val[4][4];
        float ssum[4] = {0.f, 0.f, 0.f, 0.f}, dsum[4] = {0.f, 0.f, 0.f, 0.f};
#pragma unroll
        for (int ct = 0; ct < 4; ++ct) {
            int cg2 = chalf + ct * 16 + colg;
            float bv = bias[n0 + ct * 16 + colg];
            float asr = avec[r * 256 + cg2];
            float ads = avec[r * 256 + 128 + cg2];
#pragma unroll
            for (int reg = 0; reg < 4; ++reg) {
                float v = acc[ct][reg] + bv;
                val[ct][reg] = v;
                ssum[reg] += v * asr;
                dsum[reg] += v * ads;
            }
        }
#pragma unroll
        for (int mk = 1; mk < 16; mk <<= 1)
#pragma unroll
            for (int reg = 0; reg < 4; ++reg) {
                ssum[reg] += __shfl_xor(ssum[reg], mk);
                dsum[reg] += __shfl_xor(dsum[reg], mk);
            }
        if (colg == 0) {
            int half = (n0 >> 6) & 1;
#pragma unroll
            for (int reg = 0; reg < 4; ++reg) {
                int row = m0 + w * 16 + rquad * 4 + reg;
                srcp[half * 40960 + row * 5 + r] = ssum[reg];
                dstp[half * 40960 + row * 5 + r] = dsum[reg];
            }
        }
        {
            const int joct = (jb >> 3) + w * 2 + (rquad >> 1);
            const size_t tile = (size_t)((b * 5 + r) * 32 + joct) * 1024;
            const int sub = (rquad & 1) * 4;
#pragma unroll
            for (int ct = 0; ct < 4; ++ct) {
                int c = chalf + ct * 16 + colg;
                uint2 pk;
                pk.x = (unsigned)f2bf(val[ct][0]) | ((unsigned)f2bf(val[ct][1]) << 16);
                pk.y = (unsigned)f2bf(val[ct][2]) | ((unsigned)f2bf(val[ct][3]) << 16);
                *(uint2*)&hTf[tile + (size_t)c * 8 + sub] = pk;
            }
        }
    }
}

// ======================= agg phase (device function) =======================
// units vb in [0,512): js = vb&1 (128 j), itile = (vb>>1)&7 (32 i), b = vb>>4.
// 512 threads. LDS: Ps 40960 B @0, Ss @40960, Ds2l @41600, Zrow @44160.
__device__ __forceinline__ void agg_phase(
    int blk, int nvb, int t, char* smem,
    const unsigned short* __restrict__ hTf,
    const float* __restrict__ srcp, const float* __restrict__ dstp,
    const unsigned char* __restrict__ maskp,
    float* __restrict__ aggP, float* __restrict__ Zpart)
{
    unsigned short* Ps = (unsigned short*)smem;
    float* Ss = (float*)(smem + 40960);
    float* Ds2l = (float*)(smem + 41600);
    float* Zrow = (float*)(smem + 44160);
    for (int vb = blk; vb < 512; vb += nvb) {
        const int js = vb & 1, itile = (vb >> 1) & 7, b = vb >> 4;
        const int ib = b * 256 + itile * 32;
        __syncthreads();   // LDS reuse guard (prev iteration / prev phase)
        if (t < 160) Ss[t] = srcp[(size_t)ib * 5 + t] + srcp[40960 + (size_t)ib * 5 + t];
        if (t >= 160 && t < 192) Zrow[t - 160] = 0.f;
        for (int idx = t; idx < 640; idx += 512) {
            int jl = idx & 127, rr = idx >> 7;
            size_t o = (size_t)(b * 256 + js * 128 + jl) * 5 + rr;
            Ds2l[rr * 128 + jl] = dstp[o] + dstp[40960 + o];
        }
        __syncthreads();
#pragma unroll
        for (int it = 0; it < 5; ++it) {
            int p = it * 512 + t;
            int lane8 = p & 63, chunkrow = p >> 6;
            int colg8 = lane8 & 15, kq = lane8 >> 4;
            int ih = (chunkrow >= 20) ? 1 : 0;
            int s = chunkrow - ih * 20;
            int i = ih * 16 + colg8;
            int rr = s >> 2;
            int j0l = (s & 3) * 32 + kq * 8;
            uint2 mk8 = *(const uint2*)&maskp[((size_t)(ib + i) << 8) + js * 128 + j0l];
            float sv = Ss[i * 5 + rr];
            float esum = 0.f;
            bf16x8 pv;
#pragma unroll
            for (int e = 0; e < 8; ++e) {
                unsigned mb = ((e < 4 ? (mk8.x >> (8 * e)) : (mk8.y >> (8 * (e - 4)))) >> rr) & 1u;
                float v = lrelu(sv + Ds2l[rr * 128 + j0l + e]);
                float ev = mb ? __expf(v) : 0.f;
                unsigned short q = f2bf(ev);
                pv[e] = (short)q;
                esum += __uint_as_float((unsigned)q << 16);
            }
            *(bf16x8*)&Ps[p * 8] = pv;
            atomicAdd(&Zrow[i], esum);
        }
        __syncthreads();
        if (t < 32) Zpart[(size_t)js * 8192 + ib + t] = Zrow[t];

        const int w = t >> 6, lane = t & 63;
        const int ih = w & 1, ch = w >> 1;
        const int colg = lane & 15, rquad = lane >> 4;
        f32x4 acc[2] = {};
        const size_t bbase = (size_t)(b * 5) * 32 * 1024;
#pragma unroll
        for (int s = 0; s < 20; ++s) {
            bf16x8 af = *(const bf16x8*)&Ps[((ih * 20 + s) * 64 + lane) * 8];
            const int rr = s >> 2;
            const int joct = js * 16 + (s & 3) * 4 + rquad;
            const size_t tbase = bbase + (size_t)(rr * 32 + joct) * 1024;
#pragma unroll
            for (int ct = 0; ct < 2; ++ct) {
                int c = ch * 32 + ct * 16 + colg;
                bf16x8 bfv = *(const bf16x8*)&hTf[tbase + (size_t)c * 8];
                acc[ct] = __builtin_amdgcn_mfma_f32_16x16x32_bf16(af, bfv, acc[ct], 0, 0, 0);
            }
        }
        float* op = aggP + (size_t)js * 1048576;
        const int irow = ib + ih * 16 + rquad * 4;
#pragma unroll
        for (int ct = 0; ct < 2; ++ct) {
            int c = ch * 32 + ct * 16 + colg;
#pragma unroll
            for (int reg = 0; reg < 4; ++reg)
                op[(size_t)(irow + reg) * 128 + c] = acc[ct][reg];
        }
    }
}

// ======================= mega kernel =======================
__global__ __launch_bounds__(512, 4) void k_mega(
    const float* __restrict__ x, const float* __restrict__ y_atoms,
    const int* __restrict__ bonds,
    const float* __restrict__ W1, const float* __restrict__ b1, const float* __restrict__ a1,
    const float* __restrict__ W2, const float* __restrict__ b2, const float* __restrict__ a2,
    const float* __restrict__ W3, const float* __restrict__ b3, const float* __restrict__ a3,
    const float* __restrict__ We1, const float* __restrict__ be1,
    const float* __restrict__ We2, const float* __restrict__ be2,
    const float* __restrict__ We3, const float* __restrict__ be3,
    unsigned short* __restrict__ WT1, unsigned short* __restrict__ WT2,
    unsigned short* __restrict__ WT3, float* __restrict__ We1T,
    unsigned char* __restrict__ maskp,
    float* __restrict__ srcp, float* __restrict__ dstp,
    float* __restrict__ aggP, float* __restrict__ Zpart,
    unsigned short* __restrict__ hTf,
    float* __restrict__ poolS, float* __restrict__ poolM,
    float* __restrict__ z1g, float* __restrict__ out)
{
    __shared__ __align__(16) char smem[44288];
    cg::grid_group grid = cg::this_grid();
    const int blk = blockIdx.x;
    const int nvb = gridDim.x;
    const int t = threadIdx.x;

    // ---------------- phase P: prep (weights + mask pack) ----------------
    for (int vb = blk; vb < 62; vb += nvb) {
        if (vb < 30) {
            if (t < 256) {
                int layer = vb / 10, nt = vb % 10;
                const float* W; unsigned short* WT; int K;
                if (layer == 0)      { W = W1; WT = WT1; K = 64; }
                else if (layer == 1) { W = W2; WT = WT2; K = 128; }
                else                 { W = W3; WT = WT3; K = 128; }
                int n = nt * 64 + (t & 63);
                for (int kg = (t >> 6); kg < K / 8; kg += 4) {
                    bf16x8 v;
#pragma unroll
                    for (int e = 0; e < 8; ++e) v[e] = (short)f2bf(W[(size_t)(kg * 8 + e) * 640 + n]);
                    *(bf16x8*)&WT[(size_t)n * K + kg * 8] = v;
                }
            }
        } else {
            int bt = vb - 30;
            float* Ls = (float*)smem;   // [40][256]
            __syncthreads();
            if (t < 256) {
                for (int kk = 0; kk < 40; ++kk)
                    Ls[kk * 256 + t] = We1[(size_t)(bt * 40 + kk) * 256 + t];
            }
            __syncthreads();
            if (t < 256) {
#pragma unroll
                for (int q = 0; q < 10; ++q) {
                    float4 v;
                    v.x = Ls[(q * 4 + 0) * 256 + t]; v.y = Ls[(q * 4 + 1) * 256 + t];
                    v.z = Ls[(q * 4 + 2) * 256 + t]; v.w = Ls[(q * 4 + 3) * 256 + t];
                    *(float4*)&We1T[(size_t)t * 1280 + bt * 40 + q * 4] = v;
                }
            }
        }
    }
    {
        const size_t step = (size_t)nvb * 512 * 8;
        for (size_t base = ((size_t)blk * 512 + t) * 8; base < 2097152ull; base += step) {
            unsigned mb[8];
#pragma unroll
            for (int e = 0; e < 8; ++e) {
                const int* p = bonds + (base + e) * 5;
                unsigned m = 0;
#pragma unroll
                for (int r = 0; r < 5; ++r) m |= (p[r] == 1) ? (1u << r) : 0u;
                mb[e] = m;
            }
            uint2 pk;
            pk.x = mb[0] | (mb[1] << 8) | (mb[2] << 16) | (mb[3] << 24);
            pk.y = mb[4] | (mb[5] << 8) | (mb[6] << 16) | (mb[7] << 24);
            *(uint2*)&maskp[base] = pk;
        }
    }
    grid.sync();

    // ---------------- layer 1 ----------------
    gemm_phase<64, 0>(blk, nvb, t, y_atoms, nullptr, nullptr, WT1, b1, a1, srcp, dstp, hTf);
    grid.sync();
    agg_phase(blk, nvb, t, smem, hTf, srcp, dstp, maskp, aggP, Zpart);
    grid.sync();
    // ---------------- layer 2 ----------------
    gemm_phase<128, 1>(blk, nvb, t, nullptr, aggP, Zpart, WT2, b2, a2, srcp, dstp, hTf);
    grid.sync();
    agg_phase(blk, nvb, t, smem, hTf, srcp, dstp, maskp, aggP, Zpart);
    grid.sync();
    // ---------------- layer 3 ----------------
    gemm_phase<128, 1>(blk, nvb, t, nullptr, aggP, Zpart, WT3, b3, a3, srcp, dstp, hTf);
    grid.sync();
    agg_phase(blk, nvb, t, smem, hTf, srcp, dstp, maskp, aggP, Zpart);
    grid.sync();

    // ---------------- pool: units U in [0,256): nc = U&7, b = U>>3 ----------------
    {
        const int su = t >> 8, tl = t & 255;
        for (int U = blk * 2 + su; U < 256; U += nvb * 2) {
            const int nc = U & 7, b = U >> 3;
            float* Zl = (float*)smem + su * 32;
            float* Sh = (float*)smem + 64 + su * 256;
            float* Mh = (float*)smem + 64 + 512 + su * 256;
            const int c = tl & 127, sub = tl >> 7;
            __syncthreads();
            if (tl < 32) {
                int rowg = b * 256 + nc * 32 + tl;
                Zl[tl] = 1.f / (Zpart[rowg] + Zpart[8192 + rowg]);
            }
            __syncthreads();
            float sm = 0.f, mx = -3.4e38f;
#pragma unroll
            for (int nn = 0; nn < 16; ++nn) {
                int nl = sub * 16 + nn;
                size_t o = (size_t)(b * 256 + nc * 32 + nl) * 128 + c;
                float v = (aggP[o] + aggP[o + 1048576]) * Zl[nl];
                sm += v; mx = fmaxf(mx, v);
            }
            Sh[sub * 128 + c] = sm; Mh[sub * 128 + c] = mx;
            __syncthreads();
            if (tl < 128) {
                poolS[(b * 8 + nc) * 128 + tl] = Sh[tl] + Sh[128 + tl];
                poolM[(b * 8 + nc) * 128 + tl] = fmaxf(Mh[tl], Mh[128 + tl]);
            }
        }
    }
    grid.sync();

    // ---------------- mlp1: units vb in [0,512): og = vb&15, b = vb>>4 ----------------
    for (int vb = blk; vb < 512; vb += nvb) {
        const int og = vb & 15, b = vb >> 4;
        float* zs = (float*)smem;   // 1280 floats
        __syncthreads();
        if (t < 256) {
            for (int i = t; i < 1024; i += 256) zs[i] = x[b * 1024 + i];
            if (t < 128) {
                float s = 0.f;
#pragma unroll
                for (int nc2 = 0; nc2 < 8; ++nc2) s += poolS[(b * 8 + nc2) * 128 + t];
                zs[1024 + t] = s * (1.f / 256.f);
            } else {
                int f = t - 128;
                float mx = -3.4e38f;
#pragma unroll
                for (int nc2 = 0; nc2 < 8; ++nc2) mx = fmaxf(mx, poolM[(b * 8 + nc2) * 128 + f]);
                zs[1152 + f] = mx;
            }
        }
        __syncthreads();
        if (t < 256) {
            int w2 = t >> 6, lane2 = t & 63;
#pragma unroll
            for (int oo = 0; oo < 4; ++oo) {
                int o = og * 16 + w2 * 4 + oo;
                float s = 0.f;
#pragma unroll
                for (int i = 0; i < 20; ++i) {
                    int k = i * 64 + lane2;
                    s += zs[k] * We1T[(size_t)o * 1280 + k];
                }
#pragma unroll
                for (int off = 32; off > 0; off >>= 1) s += __shfl_down(s, off);
                if (lane2 == 0) z1g[b * 256 + o] = lrelu(s + be1[o]);
            }
        }
    }
    grid.sync();

    // ---------------- mlp23: units vb in [0,32) = b ----------------
    for (int vb = blk; vb < 32; vb += nvb) {
        float* zs = (float*)smem;          // 256
        float* z2s = (float*)smem + 256;   // 32
        __syncthreads();
        if (t < 256) zs[t] = z1g[vb * 256 + t];
        __syncthreads();
        if (t < 32) {
            float s2 = be2[t];
            for (int k = 0; k < 256; ++k) s2 += zs[k] * We2[k * 32 + t];
            z2s[t] = lrelu(s2);
        }
        __syncthreads();
        if (t == 0) {
            float s3 = be3[0];
#pragma unroll
            for (int k = 0; k < 32; ++k) s3 += z2s[k] * We3[k];
            out[vb] = s3;
        }
    }
}

// ---------------- workspace layout ----------------
constexpr size_t O_MASK  = 0;                                  // 2 MB
constexpr size_t O_SRCP  = 2097152;                            // 2 x 40960 floats
constexpr size_t O_DSTP  = O_SRCP + 2ull * 40960 * 4;
constexpr size_t O_AGG   = O_DSTP + 2ull * 40960 * 4;          // 2 x 8192 x 128 fp32
constexpr size_t O_ZP    = O_AGG + 2ull * 1048576 * 4;         // 2 x 8192 floats
constexpr size_t O_HT    = O_ZP + 2ull * 8192 * 4;             // 10.5 MB
constexpr size_t O_WT1   = O_HT + 5242880ull * 2;
constexpr size_t O_WT2   = O_WT1 + 640ull * 64 * 2;
constexpr size_t O_WT3   = O_WT2 + 640ull * 128 * 2;
constexpr size_t O_WE1T  = O_WT3 + 640ull * 128 * 2;           // 1.31 MB
constexpr size_t O_POOLS = O_WE1T + 256ull * 1280 * 4;
constexpr size_t O_POOLM = O_POOLS + 32ull * 8 * 128 * 4;
constexpr size_t O_Z1    = O_POOLM + 32ull * 8 * 128 * 4;      // 32 KB

extern "C" void kernel_launch(void* const* d_in, const int* in_sizes, int n_in,
                              void* d_out, int out_size, void* d_ws, size_t ws_size,
                              hipStream_t stream) {
    const float* x       = (const float*)d_in[0];
    const float* y_atoms = (const float*)d_in[1];
    const int*   y_bonds = (const int*)d_in[2];
    const float* W1 = (const float*)d_in[3];
    const float* b1 = (const float*)d_in[4];
    const float* a1 = (const float*)d_in[5];
    const float* W2 = (const float*)d_in[6];
    const float* b2 = (const float*)d_in[7];
    const float* a2 = (const float*)d_in[8];
    const float* W3 = (const float*)d_in[9];
    const float* b3 = (const float*)d_in[10];
    const float* a3 = (const float*)d_in[11];
    const float* We1 = (const float*)d_in[12];
    const float* be1 = (const float*)d_in[13];
    const float* We2 = (const float*)d_in[14];
    const float* be2 = (const float*)d_in[15];
    const float* We3 = (const float*)d_in[16];
    const float* be3 = (const float*)d_in[17];
    float* out = (float*)d_out;

    char* ws = (char*)d_ws;
    unsigned char* maskp = (unsigned char*)(ws + O_MASK);
    float* srcp = (float*)(ws + O_SRCP);
    float* dstp = (float*)(ws + O_DSTP);
    float* aggP = (float*)(ws + O_AGG);
    float* Zpart = (float*)(ws + O_ZP);
    unsigned short* hTf = (unsigned short*)(ws + O_HT);
    unsigned short* WT1 = (unsigned short*)(ws + O_WT1);
    unsigned short* WT2 = (unsigned short*)(ws + O_WT2);
    unsigned short* WT3 = (unsigned short*)(ws + O_WT3);
    float* We1T  = (float*)(ws + O_WE1T);
    float* poolS = (float*)(ws + O_POOLS);
    float* poolM = (float*)(ws + O_POOLM);
    float* z1g   = (float*)(ws + O_Z1);

    // co-residency-safe grid size (query is host-only, capture-safe)
    int maxPerCU = 0;
    hipOccupancyMaxActiveBlocksPerMultiprocessor(&maxPerCU, (const void*)k_mega, 512, 0);
    int nblocks = maxPerCU * 256;
    if (nblocks > 512) nblocks = 512;
    if (nblocks < 1) nblocks = 256;

    void* args[] = {
        (void*)&x, (void*)&y_atoms, (void*)&y_bonds,
        (void*)&W1, (void*)&b1, (void*)&a1,
        (void*)&W2, (void*)&b2, (void*)&a2,
        (void*)&W3, (void*)&b3, (void*)&a3,
        (void*)&We1, (void*)&be1, (void*)&We2, (void*)&be2,
        (void*)&We3, (void*)&be3,
        (void*)&WT1, (void*)&WT2, (void*)&WT3, (void*)&We1T,
        (void*)&maskp,
        (void*)&srcp, (void*)&dstp, (void*)&aggP, (void*)&Zpart,
        (void*)&hTf,
        (void*)&poolS, (void*)&poolM, (void*)&z1g, (void*)&out
    };
    hipLaunchCooperativeKernel((const void*)k_mega, dim3(nblocks), dim3(512), args, 0, stream);
}

// Round 12
// 264.652 us; speedup vs baseline: 2.1859x; 2.1859x over previous
//
#include <hip/hip_runtime.h>
#include <cstddef>

#define BB 32
#define NN 256
#define RR 5

typedef __attribute__((ext_vector_type(8))) short bf16x8;
typedef __attribute__((ext_vector_type(4))) float f32x4;

__device__ __forceinline__ float lrelu(float x) { return x >= 0.f ? x : 0.2f * x; }
// RNE float -> bf16
__device__ __forceinline__ unsigned short f2bf(float x) {
    unsigned u = __float_as_uint(x);
    u += 0x7FFFu + ((u >> 16) & 1u);
    return (unsigned short)(u >> 16);
}

// =======================================================================================
// k_prep: fused one-time prep.
// blocks 0..29: W (K x 640 fp32) -> WT (640 x K bf16); blocks 30..61: We1 -> We1T;
// blocks 62..8253: pack y_bonds -> maskp (5-bit per (b,i,j)).
// =======================================================================================
__global__ __launch_bounds__(256) void k_prep(const float* __restrict__ W1,
                                              const float* __restrict__ W2,
                                              const float* __restrict__ W3,
                                              const float* __restrict__ We1,
                                              const int* __restrict__ bonds,
                                              unsigned short* __restrict__ WT1,
                                              unsigned short* __restrict__ WT2,
                                              unsigned short* __restrict__ WT3,
                                              float* __restrict__ We1T,
                                              unsigned char* __restrict__ maskp) {
    __shared__ float Ls[40][256];
    int blk = blockIdx.x;
    int t = threadIdx.x;
    if (blk < 30) {
        int layer = blk / 10, nt = blk % 10;
        const float* W;
        unsigned short* WT;
        int K;
        if (layer == 0)      { W = W1; WT = WT1; K = 64; }
        else if (layer == 1) { W = W2; WT = WT2; K = 128; }
        else                 { W = W3; WT = WT3; K = 128; }
        int n = nt * 64 + (t & 63);
        for (int kg = (int)(t >> 6); kg < K / 8; kg += 4) {
            bf16x8 v;
#pragma unroll
            for (int e = 0; e < 8; ++e) v[e] = (short)f2bf(W[(size_t)(kg * 8 + e) * 640 + n]);
            *(bf16x8*)&WT[(size_t)n * K + kg * 8] = v;
        }
    } else if (blk < 62) {
        int bt = blk - 30;                         // k-range [bt*40, bt*40+40)
        for (int kk = 0; kk < 40; ++kk)
            Ls[kk][t] = We1[(size_t)(bt * 40 + kk) * 256 + t];
        __syncthreads();
#pragma unroll
        for (int q = 0; q < 10; ++q) {
            float4 v;
            v.x = Ls[q * 4 + 0][t]; v.y = Ls[q * 4 + 1][t];
            v.z = Ls[q * 4 + 2][t]; v.w = Ls[q * 4 + 3][t];
            *(float4*)&We1T[(size_t)t * 1280 + bt * 40 + q * 4] = v;
        }
    } else {
        int idx = (blk - 62) * 256 + t;
        const int* p = bonds + (size_t)idx * 5;
        unsigned m = 0;
#pragma unroll
        for (int r = 0; r < 5; ++r) m |= (p[r] == 1) ? (1u << r) : 0u;
        maskp[idx] = (unsigned char)m;
    }
}

// =======================================================================================
// gemm_h: h = A(8192 x K) @ W(K x 640) + bias, MFMA bf16 (fp32 accum), no LDS staging.
// MODE 0: A = fp32 Af32 (layer 1). MODE 1: A = (aggP0+aggP1)/(Z0+Z1), leaky (layers 2/3).
// Emits src/dst partial dots (2 halves) and hTf fragment-native:
//   hTf[((b*5 + r)*32 + joct)*1024 + c*8 + e]   (joct = j/8, e = j%8)
// grid (10 n-tiles of 64, 128 m-tiles of 64), 256 threads = 4 waves.
// =======================================================================================
template <int K, int MODE>
__global__ __launch_bounds__(256) void k_gemm_h(const float* __restrict__ Af32,
                                                const float* __restrict__ aggP,
                                                const float* __restrict__ Zpart,
                                                const unsigned short* __restrict__ WTg,
                                                const float* __restrict__ bias,
                                                const float* __restrict__ avec,
                                                float* __restrict__ srcp,
                                                float* __restrict__ dstp,
                                                unsigned short* __restrict__ hTf) {
    const int t = threadIdx.x;
    const int n0 = blockIdx.x * 64, m0 = blockIdx.y * 64;
    const int w = t >> 6, lane = t & 63;
    const int colg = lane & 15, rquad = lane >> 4;
    const int m = m0 + w * 16 + colg;        // A row this lane reads
    const int koff = rquad * 8;

    float zi = 0.f;
    if (MODE == 1) zi = 1.f / (Zpart[m] + Zpart[8192 + m]);

    f32x4 acc[4] = {};
#pragma unroll
    for (int kk = 0; kk < K; kk += 32) {
        bf16x8 af;
        size_t off = (size_t)m * K + kk + koff;
        if (MODE == 1) {
            float4 a0 = *(const float4*)&aggP[off];
            float4 a1 = *(const float4*)&aggP[off + 4];
            float4 b0 = *(const float4*)&aggP[off + 1048576];
            float4 b1 = *(const float4*)&aggP[off + 1048576 + 4];
            af[0] = (short)f2bf(lrelu((a0.x + b0.x) * zi));
            af[1] = (short)f2bf(lrelu((a0.y + b0.y) * zi));
            af[2] = (short)f2bf(lrelu((a0.z + b0.z) * zi));
            af[3] = (short)f2bf(lrelu((a0.w + b0.w) * zi));
            af[4] = (short)f2bf(lrelu((a1.x + b1.x) * zi));
            af[5] = (short)f2bf(lrelu((a1.y + b1.y) * zi));
            af[6] = (short)f2bf(lrelu((a1.z + b1.z) * zi));
            af[7] = (short)f2bf(lrelu((a1.w + b1.w) * zi));
        } else {
            float4 q0 = *(const float4*)&Af32[off];
            float4 q1 = *(const float4*)&Af32[off + 4];
            af[0] = (short)f2bf(q0.x); af[1] = (short)f2bf(q0.y);
            af[2] = (short)f2bf(q0.z); af[3] = (short)f2bf(q0.w);
            af[4] = (short)f2bf(q1.x); af[5] = (short)f2bf(q1.y);
            af[6] = (short)f2bf(q1.z); af[7] = (short)f2bf(q1.w);
        }
#pragma unroll
        for (int ct = 0; ct < 4; ++ct) {
            bf16x8 bfv = *(const bf16x8*)&WTg[(size_t)(n0 + ct * 16 + colg) * K + kk + koff];
            acc[ct] = __builtin_amdgcn_mfma_f32_16x16x32_bf16(af, bfv, acc[ct], 0, 0, 0);
        }
    }

    // ---- epilogue: bias, src/dst partial dots (shfl-reduce over colg), hTf stores ----
    const int r = n0 >> 7, chalf = n0 & 127;
    const int b = m0 >> 8, jb = m0 & 255;
    float val[4][4];
    float ssum[4] = {0.f, 0.f, 0.f, 0.f}, dsum[4] = {0.f, 0.f, 0.f, 0.f};
#pragma unroll
    for (int ct = 0; ct < 4; ++ct) {
        int cg = chalf + ct * 16 + colg;
        float bv = bias[n0 + ct * 16 + colg];
        float asr = avec[r * 256 + cg];
        float ads = avec[r * 256 + 128 + cg];
#pragma unroll
        for (int reg = 0; reg < 4; ++reg) {
            float v = acc[ct][reg] + bv;
            val[ct][reg] = v;
            ssum[reg] += v * asr;
            dsum[reg] += v * ads;
        }
    }
#pragma unroll
    for (int mk = 1; mk < 16; mk <<= 1)
#pragma unroll
        for (int reg = 0; reg < 4; ++reg) {
            ssum[reg] += __shfl_xor(ssum[reg], mk);
            dsum[reg] += __shfl_xor(dsum[reg], mk);
        }
    if (colg == 0) {
        int half = (n0 >> 6) & 1;
#pragma unroll
        for (int reg = 0; reg < 4; ++reg) {
            int row = m0 + w * 16 + rquad * 4 + reg;
            srcp[half * 40960 + row * 5 + r] = ssum[reg];
            dstp[half * 40960 + row * 5 + r] = dsum[reg];
        }
    }
    // hTf direct stores: reg-quad = 4 consecutive j (8 B contiguous)
    {
        const int joct = (jb >> 3) + w * 2 + (rquad >> 1);
        const size_t tile = (size_t)((b * 5 + r) * 32 + joct) * 1024;
        const int sub = (rquad & 1) * 4;
#pragma unroll
        for (int ct = 0; ct < 4; ++ct) {
            int c = chalf + ct * 16 + colg;
            uint2 pk;
            pk.x = (unsigned)f2bf(val[ct][0]) | ((unsigned)f2bf(val[ct][1]) << 16);
            pk.y = (unsigned)f2bf(val[ct][2]) | ((unsigned)f2bf(val[ct][3]) << 16);
            *(uint2*)&hTf[tile + (size_t)c * 8 + sub] = pk;
        }
    }
}

// =======================================================================================
// k_agg: grid (2 js of 128 j, 16 i-tiles of 16, 32 b) = 1024 blocks, 256 threads = 4 waves.
// Unnormalized e = mask ? exp(lrelu(src+dst)) : 0 (bf16) in LDS (16 i x 640 k = 20 KB).
// Writes aggP[js][row][c] fp32 and Zpart[js][row]. ~23.4 KB LDS -> 6 blocks/CU capacity.
// Wave w covers c-quarter [w*32, w*32+32), all 16 i; 20 K-steps x 2 MFMA.
// =======================================================================================
__global__ __launch_bounds__(256) void k_agg(const unsigned short* __restrict__ hTf,
                                             const float* __restrict__ srcp,
                                             const float* __restrict__ dstp,
                                             const unsigned char* __restrict__ maskp,
                                             float* __restrict__ aggP,
                                             float* __restrict__ Zpart) {
    __shared__ unsigned short Ps[10240];          // 20 s x 64 chunks x 8 bf16 = 20 KB
    __shared__ float Ss[80], Ds2l[640], Zrow[16];
    const int t = threadIdx.x;
    const int js = blockIdx.x, itile = blockIdx.y, b = blockIdx.z;
    const int ib = b * 256 + itile * 16;

    if (t < 80) Ss[t] = srcp[(size_t)ib * 5 + t] + srcp[40960 + (size_t)ib * 5 + t];
    if (t >= 80 && t < 96) Zrow[t - 80] = 0.f;
    for (int idx = t; idx < 640; idx += 256) {
        int jl = idx & 127, rr = idx >> 7;
        size_t o = (size_t)(b * 256 + js * 128 + jl) * 5 + rr;
        Ds2l[rr * 128 + jl] = dstp[o] + dstp[40960 + o];
    }
    __syncthreads();

    // P generation: 1280 chunks of 8; thread t -> chunks it*256+t (i = t&15 fixed)
    {
        const int i = t & 15;
        float esum = 0.f;
#pragma unroll
        for (int it = 0; it < 5; ++it) {
            int p = it * 256 + t;
            int lane8 = p & 63, s = p >> 6;           // s in [0,20)
            int kq = lane8 >> 4;
            int k0 = s * 32 + kq * 8;                 // k0 in [0,640)
            int rr = k0 >> 7, j0l = k0 & 127;
            uint2 mk8 = *(const uint2*)&maskp[((size_t)(ib + i) << 8) + js * 128 + j0l];
            float sv = Ss[i * 5 + rr];
            bf16x8 pv;
#pragma unroll
            for (int e = 0; e < 8; ++e) {
                unsigned mb = ((e < 4 ? (mk8.x >> (8 * e)) : (mk8.y >> (8 * (e - 4)))) >> rr) & 1u;
                float v = lrelu(sv + Ds2l[rr * 128 + j0l + e]);
                float ev = mb ? __expf(v) : 0.f;
                unsigned short q = f2bf(ev);
                pv[e] = (short)q;
                esum += __uint_as_float((unsigned)q << 16);
            }
            *(bf16x8*)&Ps[p * 8] = pv;
        }
        atomicAdd(&Zrow[i], esum);
    }
    __syncthreads();
    if (t < 16) Zpart[(size_t)js * 8192 + ib + t] = Zrow[t];

    // MFMA: wave w -> c in [w*32, w*32+32); 20 steps over (r, j-window)
    const int w = t >> 6, lane = t & 63;
    const int colg = lane & 15, rquad = lane >> 4;
    f32x4 acc[2] = {};
    const size_t bbase = (size_t)(b * 5) * 32 * 1024;
#pragma unroll
    for (int s = 0; s < 20; ++s) {
        bf16x8 af = *(const bf16x8*)&Ps[(s * 64 + lane) * 8];
        const int rr = s >> 2;
        const int joct = js * 16 + (s & 3) * 4 + rquad;
        const size_t tbase = bbase + (size_t)(rr * 32 + joct) * 1024;
#pragma unroll
        for (int ct = 0; ct < 2; ++ct) {
            int c = w * 32 + ct * 16 + colg;
            bf16x8 bfv = *(const bf16x8*)&hTf[tbase + (size_t)c * 8];
            acc[ct] = __builtin_amdgcn_mfma_f32_16x16x32_bf16(af, bfv, acc[ct], 0, 0, 0);
        }
    }
    float* op = aggP + (size_t)js * 1048576;      // 8192*128
    const int irow = ib + rquad * 4;
#pragma unroll
    for (int ct = 0; ct < 2; ++ct) {
        int c = w * 32 + ct * 16 + colg;
#pragma unroll
        for (int reg = 0; reg < 4; ++reg)
            op[(size_t)(irow + reg) * 128 + c] = acc[ct][reg];
    }
}

// =======================================================================================
// k_pool: per (n-chunk of 32, b): chunk sum & max of h3 = (aggP0+aggP1)/Z over n.
// grid (8, 32), 256 threads. Coalesced over c.
// =======================================================================================
__global__ __launch_bounds__(256) void k_pool(const float* __restrict__ aggP,
                                              const float* __restrict__ Zpart,
                                              float* __restrict__ poolS,
                                              float* __restrict__ poolM) {
    int nc = blockIdx.x, b = blockIdx.y;
    int t = threadIdx.x;
    int c = t & 127, sub = t >> 7;
    __shared__ float Zl[32];
    __shared__ float Sh[2][128], Mh[2][128];
    if (t < 32) {
        int rowg = b * 256 + nc * 32 + t;
        Zl[t] = 1.f / (Zpart[rowg] + Zpart[8192 + rowg]);
    }
    __syncthreads();
    float sm = 0.f, mx = -3.4e38f;
#pragma unroll
    for (int nn = 0; nn < 16; ++nn) {
        int nl = sub * 16 + nn;
        size_t o = (size_t)(b * 256 + nc * 32 + nl) * 128 + c;
        float v = (aggP[o] + aggP[o + 1048576]) * Zl[nl];
        sm += v; mx = fmaxf(mx, v);
    }
    Sh[sub][c] = sm; Mh[sub][c] = mx;
    __syncthreads();
    if (t < 128) {
        poolS[(b * 8 + nc) * 128 + t] = Sh[0][t] + Sh[1][t];
        poolM[(b * 8 + nc) * 128 + t] = fmaxf(Mh[0][t], Mh[1][t]);
    }
}

// =======================================================================================
// k_head: fused MLP (layers 1-3). One block per b, 256 threads.
// z = [x | mean | max] (1280) -> z1 (256, wave-per-4-outputs shfl GEMV over 16 passes)
// -> z2 (32) -> out (1).
// =======================================================================================
__global__ __launch_bounds__(256) void k_head(const float* __restrict__ x,
                                              const float* __restrict__ poolS,
                                              const float* __restrict__ poolM,
                                              const float* __restrict__ We1T,
                                              const float* __restrict__ be1,
                                              const float* __restrict__ We2,
                                              const float* __restrict__ be2,
                                              const float* __restrict__ We3,
                                              const float* __restrict__ be3,
                                              float* __restrict__ out) {
    int b = blockIdx.x, t = threadIdx.x;
    __shared__ float zs[1280], z1s[256], z2s[32];
    for (int i = t; i < 1024; i += 256) zs[i] = x[b * 1024 + i];
    if (t < 128) {
        float s = 0.f;
#pragma unroll
        for (int nc = 0; nc < 8; ++nc) s += poolS[(b * 8 + nc) * 128 + t];
        zs[1024 + t] = s * (1.f / 256.f);
    } else {
        int f = t - 128;
        float mx = -3.4e38f;
#pragma unroll
        for (int nc = 0; nc < 8; ++nc) mx = fmaxf(mx, poolM[(b * 8 + nc) * 128 + f]);
        zs[1152 + f] = mx;
    }
    __syncthreads();
    int w = t >> 6, lane = t & 63;
#pragma unroll
    for (int pass = 0; pass < 16; ++pass) {
#pragma unroll
        for (int oo = 0; oo < 4; ++oo) {
            int o = pass * 16 + w * 4 + oo;
            float s = 0.f;
#pragma unroll
            for (int i = 0; i < 20; ++i) {
                int k = i * 64 + lane;
                s += zs[k] * We1T[(size_t)o * 1280 + k];
            }
#pragma unroll
            for (int off = 32; off > 0; off >>= 1) s += __shfl_down(s, off);
            if (lane == 0) z1s[o] = lrelu(s + be1[o]);
        }
    }
    __syncthreads();
    if (t < 32) {
        float s2 = be2[t];
        for (int k = 0; k < 256; ++k) s2 += z1s[k] * We2[k * 32 + t];
        z2s[t] = lrelu(s2);
    }
    __syncthreads();
    if (t == 0) {
        float s3 = be3[0];
#pragma unroll
        for (int k = 0; k < 32; ++k) s3 += z2s[k] * We3[k];
        out[b] = s3;
    }
}

// ---------------- workspace layout ----------------
constexpr size_t O_MASK  = 0;                                  // 2 MB
constexpr size_t O_SRCP  = 2097152;                            // 2 x 40960 floats
constexpr size_t O_DSTP  = O_SRCP + 2ull * 40960 * 4;
constexpr size_t O_AGG   = O_DSTP + 2ull * 40960 * 4;          // 2 x 8192 x 128 fp32
constexpr size_t O_ZP    = O_AGG + 2ull * 1048576 * 4;         // 2 x 8192 floats
constexpr size_t O_HT    = O_ZP + 2ull * 8192 * 4;             // 10.5 MB
constexpr size_t O_WT1   = O_HT + 5242880ull * 2;
constexpr size_t O_WT2   = O_WT1 + 640ull * 64 * 2;
constexpr size_t O_WT3   = O_WT2 + 640ull * 128 * 2;
constexpr size_t O_WE1T  = O_WT3 + 640ull * 128 * 2;           // 1.31 MB
constexpr size_t O_POOLS = O_WE1T + 256ull * 1280 * 4;
constexpr size_t O_POOLM = O_POOLS + 32ull * 8 * 128 * 4;

extern "C" void kernel_launch(void* const* d_in, const int* in_sizes, int n_in,
                              void* d_out, int out_size, void* d_ws, size_t ws_size,
                              hipStream_t stream) {
    const float* x       = (const float*)d_in[0];
    const float* y_atoms = (const float*)d_in[1];
    const int*   y_bonds = (const int*)d_in[2];
    const float* W1 = (const float*)d_in[3];
    const float* b1 = (const float*)d_in[4];
    const float* a1 = (const float*)d_in[5];
    const float* W2 = (const float*)d_in[6];
    const float* b2 = (const float*)d_in[7];
    const float* a2 = (const float*)d_in[8];
    const float* W3 = (const float*)d_in[9];
    const float* b3 = (const float*)d_in[10];
    const float* a3 = (const float*)d_in[11];
    const float* We1 = (const float*)d_in[12];
    const float* be1 = (const float*)d_in[13];
    const float* We2 = (const float*)d_in[14];
    const float* be2 = (const float*)d_in[15];
    const float* We3 = (const float*)d_in[16];
    const float* be3 = (const float*)d_in[17];
    float* out = (float*)d_out;

    char* ws = (char*)d_ws;
    unsigned char* maskp = (unsigned char*)(ws + O_MASK);
    float* srcp = (float*)(ws + O_SRCP);
    float* dstp = (float*)(ws + O_DSTP);
    float* aggP = (float*)(ws + O_AGG);
    float* Zpart = (float*)(ws + O_ZP);
    unsigned short* hTf = (unsigned short*)(ws + O_HT);
    unsigned short* WT1 = (unsigned short*)(ws + O_WT1);
    unsigned short* WT2 = (unsigned short*)(ws + O_WT2);
    unsigned short* WT3 = (unsigned short*)(ws + O_WT3);
    float* We1T  = (float*)(ws + O_WE1T);
    float* poolS = (float*)(ws + O_POOLS);
    float* poolM = (float*)(ws + O_POOLM);

    dim3 blk(256);

    k_prep<<<8254, blk, 0, stream>>>(W1, W2, W3, We1, y_bonds, WT1, WT2, WT3, We1T, maskp);

    // layer 1
    k_gemm_h<64, 0><<<dim3(10, 128), blk, 0, stream>>>(
        y_atoms, nullptr, nullptr, WT1, b1, a1, srcp, dstp, hTf);
    k_agg<<<dim3(2, 16, 32), blk, 0, stream>>>(hTf, srcp, dstp, maskp, aggP, Zpart);

    // layer 2
    k_gemm_h<128, 1><<<dim3(10, 128), blk, 0, stream>>>(
        nullptr, aggP, Zpart, WT2, b2, a2, srcp, dstp, hTf);
    k_agg<<<dim3(2, 16, 32), blk, 0, stream>>>(hTf, srcp, dstp, maskp, aggP, Zpart);

    // layer 3
    k_gemm_h<128, 1><<<dim3(10, 128), blk, 0, stream>>>(
        nullptr, aggP, Zpart, WT3, b3, a3, srcp, dstp, hTf);
    k_agg<<<dim3(2, 16, 32), blk, 0, stream>>>(hTf, srcp, dstp, maskp, aggP, Zpart);

    // pool + fused MLP head
    k_pool<<<dim3(8, 32), blk, 0, stream>>>(aggP, Zpart, poolS, poolM);
    k_head<<<32, blk, 0, stream>>>(x, poolS, poolM, We1T, be1, We2, be2, We3, be3, out);
}

// Round 13
// 224.346 us; speedup vs baseline: 2.5787x; 1.1797x over previous
//
#include <hip/hip_runtime.h>
#include <cstddef>

#define BB 32
#define NN 256
#define RR 5

typedef __attribute__((ext_vector_type(8))) short bf16x8;
typedef __attribute__((ext_vector_type(4))) float f32x4;

__device__ __forceinline__ float lrelu(float x) { return x >= 0.f ? x : 0.2f * x; }
// RNE float -> bf16
__device__ __forceinline__ unsigned short f2bf(float x) {
    unsigned u = __float_as_uint(x);
    u += 0x7FFFu + ((u >> 16) & 1u);
    return (unsigned short)(u >> 16);
}

// =======================================================================================
// k_prep: fused one-time prep.
// blocks 0..29: W (K x 640 fp32) -> WT (640 x K bf16); blocks 30..61: We1 -> We1T;
// blocks 62..8253: pack y_bonds -> maskp (5-bit per (b,i,j)).
// =======================================================================================
__global__ __launch_bounds__(256) void k_prep(const float* __restrict__ W1,
                                              const float* __restrict__ W2,
                                              const float* __restrict__ W3,
                                              const float* __restrict__ We1,
                                              const int* __restrict__ bonds,
                                              unsigned short* __restrict__ WT1,
                                              unsigned short* __restrict__ WT2,
                                              unsigned short* __restrict__ WT3,
                                              float* __restrict__ We1T,
                                              unsigned char* __restrict__ maskp) {
    __shared__ float Ls[40][256];
    int blk = blockIdx.x;
    int t = threadIdx.x;
    if (blk < 30) {
        int layer = blk / 10, nt = blk % 10;
        const float* W;
        unsigned short* WT;
        int K;
        if (layer == 0)      { W = W1; WT = WT1; K = 64; }
        else if (layer == 1) { W = W2; WT = WT2; K = 128; }
        else                 { W = W3; WT = WT3; K = 128; }
        int n = nt * 64 + (t & 63);
        for (int kg = (int)(t >> 6); kg < K / 8; kg += 4) {
            bf16x8 v;
#pragma unroll
            for (int e = 0; e < 8; ++e) v[e] = (short)f2bf(W[(size_t)(kg * 8 + e) * 640 + n]);
            *(bf16x8*)&WT[(size_t)n * K + kg * 8] = v;
        }
    } else if (blk < 62) {
        int bt = blk - 30;                         // k-range [bt*40, bt*40+40)
        for (int kk = 0; kk < 40; ++kk)
            Ls[kk][t] = We1[(size_t)(bt * 40 + kk) * 256 + t];
        __syncthreads();
#pragma unroll
        for (int q = 0; q < 10; ++q) {
            float4 v;
            v.x = Ls[q * 4 + 0][t]; v.y = Ls[q * 4 + 1][t];
            v.z = Ls[q * 4 + 2][t]; v.w = Ls[q * 4 + 3][t];
            *(float4*)&We1T[(size_t)t * 1280 + bt * 40 + q * 4] = v;
        }
    } else {
        int idx = (blk - 62) * 256 + t;
        const int* p = bonds + (size_t)idx * 5;
        unsigned m = 0;
#pragma unroll
        for (int r = 0; r < 5; ++r) m |= (p[r] == 1) ? (1u << r) : 0u;
        maskp[idx] = (unsigned char)m;
    }
}

// =======================================================================================
// gemm_h: h = A(8192 x K) @ W(K x 640) + bias, MFMA bf16 (fp32 accum), no LDS staging.
// MODE 0: A = fp32 Af32 (layer 1). MODE 1: A = (aggP0+aggP1)/(Z0+Z1), leaky (layers 2/3).
// Emits src/dst partial dots (2 halves) and hTf fragment-native:
//   hTf[((b*5 + r)*32 + joct)*1024 + c*8 + e]   (joct = j/8, e = j%8)
// grid (10 n-tiles of 64, 128 m-tiles of 64), 256 threads = 4 waves.
// =======================================================================================
template <int K, int MODE>
__global__ __launch_bounds__(256) void k_gemm_h(const float* __restrict__ Af32,
                                                const float* __restrict__ aggP,
                                                const float* __restrict__ Zpart,
                                                const unsigned short* __restrict__ WTg,
                                                const float* __restrict__ bias,
                                                const float* __restrict__ avec,
                                                float* __restrict__ srcp,
                                                float* __restrict__ dstp,
                                                unsigned short* __restrict__ hTf) {
    const int t = threadIdx.x;
    const int n0 = blockIdx.x * 64, m0 = blockIdx.y * 64;
    const int w = t >> 6, lane = t & 63;
    const int colg = lane & 15, rquad = lane >> 4;
    const int m = m0 + w * 16 + colg;        // A row this lane reads
    const int koff = rquad * 8;

    float zi = 0.f;
    if (MODE == 1) zi = 1.f / (Zpart[m] + Zpart[8192 + m]);

    f32x4 acc[4] = {};
#pragma unroll
    for (int kk = 0; kk < K; kk += 32) {
        bf16x8 af;
        size_t off = (size_t)m * K + kk + koff;
        if (MODE == 1) {
            float4 a0 = *(const float4*)&aggP[off];
            float4 a1 = *(const float4*)&aggP[off + 4];
            float4 b0 = *(const float4*)&aggP[off + 1048576];
            float4 b1 = *(const float4*)&aggP[off + 1048576 + 4];
            af[0] = (short)f2bf(lrelu((a0.x + b0.x) * zi));
            af[1] = (short)f2bf(lrelu((a0.y + b0.y) * zi));
            af[2] = (short)f2bf(lrelu((a0.z + b0.z) * zi));
            af[3] = (short)f2bf(lrelu((a0.w + b0.w) * zi));
            af[4] = (short)f2bf(lrelu((a1.x + b1.x) * zi));
            af[5] = (short)f2bf(lrelu((a1.y + b1.y) * zi));
            af[6] = (short)f2bf(lrelu((a1.z + b1.z) * zi));
            af[7] = (short)f2bf(lrelu((a1.w + b1.w) * zi));
        } else {
            float4 q0 = *(const float4*)&Af32[off];
            float4 q1 = *(const float4*)&Af32[off + 4];
            af[0] = (short)f2bf(q0.x); af[1] = (short)f2bf(q0.y);
            af[2] = (short)f2bf(q0.z); af[3] = (short)f2bf(q0.w);
            af[4] = (short)f2bf(q1.x); af[5] = (short)f2bf(q1.y);
            af[6] = (short)f2bf(q1.z); af[7] = (short)f2bf(q1.w);
        }
#pragma unroll
        for (int ct = 0; ct < 4; ++ct) {
            bf16x8 bfv = *(const bf16x8*)&WTg[(size_t)(n0 + ct * 16 + colg) * K + kk + koff];
            acc[ct] = __builtin_amdgcn_mfma_f32_16x16x32_bf16(af, bfv, acc[ct], 0, 0, 0);
        }
    }

    // ---- epilogue: bias, src/dst partial dots (shfl-reduce over colg), hTf stores ----
    const int r = n0 >> 7, chalf = n0 & 127;
    const int b = m0 >> 8, jb = m0 & 255;
    float val[4][4];
    float ssum[4] = {0.f, 0.f, 0.f, 0.f}, dsum[4] = {0.f, 0.f, 0.f, 0.f};
#pragma unroll
    for (int ct = 0; ct < 4; ++ct) {
        int cg = chalf + ct * 16 + colg;
        float bv = bias[n0 + ct * 16 + colg];
        float asr = avec[r * 256 + cg];
        float ads = avec[r * 256 + 128 + cg];
#pragma unroll
        for (int reg = 0; reg < 4; ++reg) {
            float v = acc[ct][reg] + bv;
            val[ct][reg] = v;
            ssum[reg] += v * asr;
            dsum[reg] += v * ads;
        }
    }
#pragma unroll
    for (int mk = 1; mk < 16; mk <<= 1)
#pragma unroll
        for (int reg = 0; reg < 4; ++reg) {
            ssum[reg] += __shfl_xor(ssum[reg], mk);
            dsum[reg] += __shfl_xor(dsum[reg], mk);
        }
    if (colg == 0) {
        int half = (n0 >> 6) & 1;
#pragma unroll
        for (int reg = 0; reg < 4; ++reg) {
            int row = m0 + w * 16 + rquad * 4 + reg;
            srcp[half * 40960 + row * 5 + r] = ssum[reg];
            dstp[half * 40960 + row * 5 + r] = dsum[reg];
        }
    }
    // hTf direct stores: reg-quad = 4 consecutive j (8 B contiguous)
    {
        const int joct = (jb >> 3) + w * 2 + (rquad >> 1);
        const size_t tile = (size_t)((b * 5 + r) * 32 + joct) * 1024;
        const int sub = (rquad & 1) * 4;
#pragma unroll
        for (int ct = 0; ct < 4; ++ct) {
            int c = chalf + ct * 16 + colg;
            uint2 pk;
            pk.x = (unsigned)f2bf(val[ct][0]) | ((unsigned)f2bf(val[ct][1]) << 16);
            pk.y = (unsigned)f2bf(val[ct][2]) | ((unsigned)f2bf(val[ct][3]) << 16);
            *(uint2*)&hTf[tile + (size_t)c * 8 + sub] = pk;
        }
    }
}

// =======================================================================================
// k_agg: grid (2 js of 128 j, 16 i-tiles of 16, 32 b) = 1024 blocks, 256 threads = 4 waves.
// Unnormalized e = mask ? exp(lrelu(src+dst)) : 0 (bf16) in LDS (16 i x 640 k = 20 KB).
// Writes aggP[js][row][c] fp32 and Zpart[js][row]. ~23.4 KB LDS -> 6 blocks/CU capacity.
// =======================================================================================
__global__ __launch_bounds__(256) void k_agg(const unsigned short* __restrict__ hTf,
                                             const float* __restrict__ srcp,
                                             const float* __restrict__ dstp,
                                             const unsigned char* __restrict__ maskp,
                                             float* __restrict__ aggP,
                                             float* __restrict__ Zpart) {
    __shared__ unsigned short Ps[10240];          // 20 s x 64 chunks x 8 bf16 = 20 KB
    __shared__ float Ss[80], Ds2l[640], Zrow[16];
    const int t = threadIdx.x;
    const int js = blockIdx.x, itile = blockIdx.y, b = blockIdx.z;
    const int ib = b * 256 + itile * 16;

    if (t < 80) Ss[t] = srcp[(size_t)ib * 5 + t] + srcp[40960 + (size_t)ib * 5 + t];
    if (t >= 80 && t < 96) Zrow[t - 80] = 0.f;
    for (int idx = t; idx < 640; idx += 256) {
        int jl = idx & 127, rr = idx >> 7;
        size_t o = (size_t)(b * 256 + js * 128 + jl) * 5 + rr;
        Ds2l[rr * 128 + jl] = dstp[o] + dstp[40960 + o];
    }
    __syncthreads();

    // P generation: 1280 chunks of 8; thread t -> chunks it*256+t (i = t&15 fixed)
    {
        const int i = t & 15;
        float esum = 0.f;
#pragma unroll
        for (int it = 0; it < 5; ++it) {
            int p = it * 256 + t;
            int lane8 = p & 63, s = p >> 6;           // s in [0,20)
            int kq = lane8 >> 4;
            int k0 = s * 32 + kq * 8;                 // k0 in [0,640)
            int rr = k0 >> 7, j0l = k0 & 127;
            uint2 mk8 = *(const uint2*)&maskp[((size_t)(ib + i) << 8) + js * 128 + j0l];
            float sv = Ss[i * 5 + rr];
            bf16x8 pv;
#pragma unroll
            for (int e = 0; e < 8; ++e) {
                unsigned mb = ((e < 4 ? (mk8.x >> (8 * e)) : (mk8.y >> (8 * (e - 4)))) >> rr) & 1u;
                float v = lrelu(sv + Ds2l[rr * 128 + j0l + e]);
                float ev = mb ? __expf(v) : 0.f;
                unsigned short q = f2bf(ev);
                pv[e] = (short)q;
                esum += __uint_as_float((unsigned)q << 16);
            }
            *(bf16x8*)&Ps[p * 8] = pv;
        }
        atomicAdd(&Zrow[i], esum);
    }
    __syncthreads();
    if (t < 16) Zpart[(size_t)js * 8192 + ib + t] = Zrow[t];

    // MFMA: wave w -> c in [w*32, w*32+32); 20 steps over (r, j-window)
    const int w = t >> 6, lane = t & 63;
    const int colg = lane & 15, rquad = lane >> 4;
    f32x4 acc[2] = {};
    const size_t bbase = (size_t)(b * 5) * 32 * 1024;
#pragma unroll
    for (int s = 0; s < 20; ++s) {
        bf16x8 af = *(const bf16x8*)&Ps[(s * 64 + lane) * 8];
        const int rr = s >> 2;
        const int joct = js * 16 + (s & 3) * 4 + rquad;
        const size_t tbase = bbase + (size_t)(rr * 32 + joct) * 1024;
#pragma unroll
        for (int ct = 0; ct < 2; ++ct) {
            int c = w * 32 + ct * 16 + colg;
            bf16x8 bfv = *(const bf16x8*)&hTf[tbase + (size_t)c * 8];
            acc[ct] = __builtin_amdgcn_mfma_f32_16x16x32_bf16(af, bfv, acc[ct], 0, 0, 0);
        }
    }
    float* op = aggP + (size_t)js * 1048576;      // 8192*128
    const int irow = ib + rquad * 4;
#pragma unroll
    for (int ct = 0; ct < 2; ++ct) {
        int c = w * 32 + ct * 16 + colg;
#pragma unroll
        for (int reg = 0; reg < 4; ++reg)
            op[(size_t)(irow + reg) * 128 + c] = acc[ct][reg];
    }
}

// =======================================================================================
// k_pool: per (n-chunk of 32, b): chunk sum & max of h3 = (aggP0+aggP1)/Z over n.
// grid (8, 32), 256 threads. Coalesced over c.
// =======================================================================================
__global__ __launch_bounds__(256) void k_pool(const float* __restrict__ aggP,
                                              const float* __restrict__ Zpart,
                                              float* __restrict__ poolS,
                                              float* __restrict__ poolM) {
    int nc = blockIdx.x, b = blockIdx.y;
    int t = threadIdx.x;
    int c = t & 127, sub = t >> 7;
    __shared__ float Zl[32];
    __shared__ float Sh[2][128], Mh[2][128];
    if (t < 32) {
        int rowg = b * 256 + nc * 32 + t;
        Zl[t] = 1.f / (Zpart[rowg] + Zpart[8192 + rowg]);
    }
    __syncthreads();
    float sm = 0.f, mx = -3.4e38f;
#pragma unroll
    for (int nn = 0; nn < 16; ++nn) {
        int nl = sub * 16 + nn;
        size_t o = (size_t)(b * 256 + nc * 32 + nl) * 128 + c;
        float v = (aggP[o] + aggP[o + 1048576]) * Zl[nl];
        sm += v; mx = fmaxf(mx, v);
    }
    Sh[sub][c] = sm; Mh[sub][c] = mx;
    __syncthreads();
    if (t < 128) {
        poolS[(b * 8 + nc) * 128 + t] = Sh[0][t] + Sh[1][t];
        poolM[(b * 8 + nc) * 128 + t] = fmaxf(Mh[0][t], Mh[1][t]);
    }
}

// =======================================================================================
// k_mlp1: z1[b][o] = lrelu( z . We1T[o] + be1[o] ), z = [x | mean | max] (1280).
// grid (16 og, 32 b) = 512 blocks, 256 threads; wave computes 4 outputs (shfl-reduce).
// =======================================================================================
__global__ __launch_bounds__(256) void k_mlp1(const float* __restrict__ x,
                                              const float* __restrict__ poolS,
                                              const float* __restrict__ poolM,
                                              const float* __restrict__ We1T,
                                              const float* __restrict__ be1,
                                              float* __restrict__ z1g) {
    int og = blockIdx.x, b = blockIdx.y;
    int t = threadIdx.x;
    __shared__ float zs[1280];
    for (int i = t; i < 1024; i += 256) zs[i] = x[b * 1024 + i];
    if (t < 128) {
        float s = 0.f;
#pragma unroll
        for (int nc = 0; nc < 8; ++nc) s += poolS[(b * 8 + nc) * 128 + t];
        zs[1024 + t] = s * (1.f / 256.f);
    } else {
        int f = t - 128;
        float mx = -3.4e38f;
#pragma unroll
        for (int nc = 0; nc < 8; ++nc) mx = fmaxf(mx, poolM[(b * 8 + nc) * 128 + f]);
        zs[1152 + f] = mx;
    }
    __syncthreads();
    int w = t >> 6, lane = t & 63;
#pragma unroll
    for (int oo = 0; oo < 4; ++oo) {
        int o = og * 16 + w * 4 + oo;
        float s = 0.f;
#pragma unroll
        for (int i = 0; i < 20; ++i) {
            int k = i * 64 + lane;
            s += zs[k] * We1T[(size_t)o * 1280 + k];
        }
#pragma unroll
        for (int off = 32; off > 0; off >>= 1) s += __shfl_down(s, off);
        if (lane == 0) z1g[b * 256 + o] = lrelu(s + be1[o]);
    }
}

// ---------------- MLP layers 2+3 ----------------
__global__ __launch_bounds__(256) void k_mlp23(const float* __restrict__ z1g,
                                               const float* __restrict__ We2,
                                               const float* __restrict__ be2,
                                               const float* __restrict__ We3,
                                               const float* __restrict__ be3,
                                               float* __restrict__ out) {
    int b = blockIdx.x, t = threadIdx.x;
    __shared__ float zs[256], z2s[32];
    zs[t] = z1g[b * 256 + t];
    __syncthreads();
    if (t < 32) {
        float s2 = be2[t];
        for (int k = 0; k < 256; ++k) s2 += zs[k] * We2[k * 32 + t];
        z2s[t] = lrelu(s2);
    }
    __syncthreads();
    if (t == 0) {
        float s3 = be3[0];
#pragma unroll
        for (int k = 0; k < 32; ++k) s3 += z2s[k] * We3[k];
        out[b] = s3;
    }
}

// ---------------- workspace layout ----------------
constexpr size_t O_MASK  = 0;                                  // 2 MB
constexpr size_t O_SRCP  = 2097152;                            // 2 x 40960 floats
constexpr size_t O_DSTP  = O_SRCP + 2ull * 40960 * 4;
constexpr size_t O_AGG   = O_DSTP + 2ull * 40960 * 4;          // 2 x 8192 x 128 fp32
constexpr size_t O_ZP    = O_AGG + 2ull * 1048576 * 4;         // 2 x 8192 floats
constexpr size_t O_HT    = O_ZP + 2ull * 8192 * 4;             // 10.5 MB
constexpr size_t O_WT1   = O_HT + 5242880ull * 2;
constexpr size_t O_WT2   = O_WT1 + 640ull * 64 * 2;
constexpr size_t O_WT3   = O_WT2 + 640ull * 128 * 2;
constexpr size_t O_WE1T  = O_WT3 + 640ull * 128 * 2;           // 1.31 MB
constexpr size_t O_POOLS = O_WE1T + 256ull * 1280 * 4;
constexpr size_t O_POOLM = O_POOLS + 32ull * 8 * 128 * 4;
constexpr size_t O_Z1    = O_POOLM + 32ull * 8 * 128 * 4;      // 32 KB

extern "C" void kernel_launch(void* const* d_in, const int* in_sizes, int n_in,
                              void* d_out, int out_size, void* d_ws, size_t ws_size,
                              hipStream_t stream) {
    const float* x       = (const float*)d_in[0];
    const float* y_atoms = (const float*)d_in[1];
    const int*   y_bonds = (const int*)d_in[2];
    const float* W1 = (const float*)d_in[3];
    const float* b1 = (const float*)d_in[4];
    const float* a1 = (const float*)d_in[5];
    const float* W2 = (const float*)d_in[6];
    const float* b2 = (const float*)d_in[7];
    const float* a2 = (const float*)d_in[8];
    const float* W3 = (const float*)d_in[9];
    const float* b3 = (const float*)d_in[10];
    const float* a3 = (const float*)d_in[11];
    const float* We1 = (const float*)d_in[12];
    const float* be1 = (const float*)d_in[13];
    const float* We2 = (const float*)d_in[14];
    const float* be2 = (const float*)d_in[15];
    const float* We3 = (const float*)d_in[16];
    const float* be3 = (const float*)d_in[17];
    float* out = (float*)d_out;

    char* ws = (char*)d_ws;
    unsigned char* maskp = (unsigned char*)(ws + O_MASK);
    float* srcp = (float*)(ws + O_SRCP);
    float* dstp = (float*)(ws + O_DSTP);
    float* aggP = (float*)(ws + O_AGG);
    float* Zpart = (float*)(ws + O_ZP);
    unsigned short* hTf = (unsigned short*)(ws + O_HT);
    unsigned short* WT1 = (unsigned short*)(ws + O_WT1);
    unsigned short* WT2 = (unsigned short*)(ws + O_WT2);
    unsigned short* WT3 = (unsigned short*)(ws + O_WT3);
    float* We1T  = (float*)(ws + O_WE1T);
    float* poolS = (float*)(ws + O_POOLS);
    float* poolM = (float*)(ws + O_POOLM);
    float* z1g   = (float*)(ws + O_Z1);

    dim3 blk(256);

    k_prep<<<8254, blk, 0, stream>>>(W1, W2, W3, We1, y_bonds, WT1, WT2, WT3, We1T, maskp);

    // layer 1
    k_gemm_h<64, 0><<<dim3(10, 128), blk, 0, stream>>>(
        y_atoms, nullptr, nullptr, WT1, b1, a1, srcp, dstp, hTf);
    k_agg<<<dim3(2, 16, 32), blk, 0, stream>>>(hTf, srcp, dstp, maskp, aggP, Zpart);

    // layer 2
    k_gemm_h<128, 1><<<dim3(10, 128), blk, 0, stream>>>(
        nullptr, aggP, Zpart, WT2, b2, a2, srcp, dstp, hTf);
    k_agg<<<dim3(2, 16, 32), blk, 0, stream>>>(hTf, srcp, dstp, maskp, aggP, Zpart);

    // layer 3
    k_gemm_h<128, 1><<<dim3(10, 128), blk, 0, stream>>>(
        nullptr, aggP, Zpart, WT3, b3, a3, srcp, dstp, hTf);
    k_agg<<<dim3(2, 16, 32), blk, 0, stream>>>(hTf, srcp, dstp, maskp, aggP, Zpart);

    // pool + parallel MLP head
    k_pool<<<dim3(8, 32), blk, 0, stream>>>(aggP, Zpart, poolS, poolM);
    k_mlp1<<<dim3(16, 32), blk, 0, stream>>>(x, poolS, poolM, We1T, be1, z1g);
    k_mlp23<<<32, blk, 0, stream>>>(z1g, We2, be2, We3, be3, out);
}

// Round 14
// 216.589 us; speedup vs baseline: 2.6710x; 1.0358x over previous
//
#include <hip/hip_runtime.h>
#include <cstddef>

#define BB 32
#define NN 256
#define RR 5

typedef __attribute__((ext_vector_type(8))) short bf16x8;
typedef __attribute__((ext_vector_type(4))) float f32x4;

__device__ __forceinline__ float lrelu(float x) { return x >= 0.f ? x : 0.2f * x; }
// RNE float -> bf16
__device__ __forceinline__ unsigned short f2bf(float x) {
    unsigned u = __float_as_uint(x);
    u += 0x7FFFu + ((u >> 16) & 1u);
    return (unsigned short)(u >> 16);
}
__device__ __forceinline__ float bf2f(unsigned short u) {
    return __uint_as_float((unsigned)u << 16);
}

// =======================================================================================
// k_prep: fused one-time prep.
// blocks 0..29: W (K x 640 fp32) -> WT (640 x K bf16); blocks 30..61: We1 -> We1T;
// blocks 62..8253: pack y_bonds -> maskp (5-bit per (b,i,j)).
// =======================================================================================
__global__ __launch_bounds__(256) void k_prep(const float* __restrict__ W1,
                                              const float* __restrict__ W2,
                                              const float* __restrict__ W3,
                                              const float* __restrict__ We1,
                                              const int* __restrict__ bonds,
                                              unsigned short* __restrict__ WT1,
                                              unsigned short* __restrict__ WT2,
                                              unsigned short* __restrict__ WT3,
                                              float* __restrict__ We1T,
                                              unsigned char* __restrict__ maskp) {
    __shared__ float Ls[40][256];
    int blk = blockIdx.x;
    int t = threadIdx.x;
    if (blk < 30) {
        int layer = blk / 10, nt = blk % 10;
        const float* W;
        unsigned short* WT;
        int K;
        if (layer == 0)      { W = W1; WT = WT1; K = 64; }
        else if (layer == 1) { W = W2; WT = WT2; K = 128; }
        else                 { W = W3; WT = WT3; K = 128; }
        int n = nt * 64 + (t & 63);
        for (int kg = (int)(t >> 6); kg < K / 8; kg += 4) {
            bf16x8 v;
#pragma unroll
            for (int e = 0; e < 8; ++e) v[e] = (short)f2bf(W[(size_t)(kg * 8 + e) * 640 + n]);
            *(bf16x8*)&WT[(size_t)n * K + kg * 8] = v;
        }
    } else if (blk < 62) {
        int bt = blk - 30;                         // k-range [bt*40, bt*40+40)
        for (int kk = 0; kk < 40; ++kk)
            Ls[kk][t] = We1[(size_t)(bt * 40 + kk) * 256 + t];
        __syncthreads();
#pragma unroll
        for (int q = 0; q < 10; ++q) {
            float4 v;
            v.x = Ls[q * 4 + 0][t]; v.y = Ls[q * 4 + 1][t];
            v.z = Ls[q * 4 + 2][t]; v.w = Ls[q * 4 + 3][t];
            *(float4*)&We1T[(size_t)t * 1280 + bt * 40 + q * 4] = v;
        }
    } else {
        int idx = (blk - 62) * 256 + t;
        const int* p = bonds + (size_t)idx * 5;
        unsigned m = 0;
#pragma unroll
        for (int r = 0; r < 5; ++r) m |= (p[r] == 1) ? (1u << r) : 0u;
        maskp[idx] = (unsigned char)m;
    }
}

// =======================================================================================
// gemm_h: h = A(8192 x K) @ W(K x 640) + bias, MFMA bf16 (fp32 accum), no LDS staging.
// MODE 0: A = fp32 Af32 (layer 1). MODE 1: A = (aggPb0+aggPb1)/(Z0+Z1), leaky (bf16 partials).
// Emits src/dst partial dots (2 halves) and hTf fragment-native:
//   hTf[((b*5 + r)*32 + joct)*1024 + c*8 + e]   (joct = j/8, e = j%8)
// grid (10 n-tiles of 64, 128 m-tiles of 64), 256 threads = 4 waves.
// =======================================================================================
template <int K, int MODE>
__global__ __launch_bounds__(256) void k_gemm_h(const float* __restrict__ Af32,
                                                const unsigned short* __restrict__ aggPb,
                                                const float* __restrict__ Zpart,
                                                const unsigned short* __restrict__ WTg,
                                                const float* __restrict__ bias,
                                                const float* __restrict__ avec,
                                                float* __restrict__ srcp,
                                                float* __restrict__ dstp,
                                                unsigned short* __restrict__ hTf) {
    const int t = threadIdx.x;
    const int n0 = blockIdx.x * 64, m0 = blockIdx.y * 64;
    const int w = t >> 6, lane = t & 63;
    const int colg = lane & 15, rquad = lane >> 4;
    const int m = m0 + w * 16 + colg;        // A row this lane reads
    const int koff = rquad * 8;

    float zi = 0.f;
    if (MODE == 1) zi = 1.f / (Zpart[m] + Zpart[8192 + m]);

    f32x4 acc[4] = {};
#pragma unroll
    for (int kk = 0; kk < K; kk += 32) {
        bf16x8 af;
        size_t off = (size_t)m * K + kk + koff;
        if (MODE == 1) {
            bf16x8 p0 = *(const bf16x8*)&aggPb[off];
            bf16x8 p1 = *(const bf16x8*)&aggPb[off + 1048576];
#pragma unroll
            for (int e = 0; e < 8; ++e) {
                float v = bf2f((unsigned short)p0[e]) + bf2f((unsigned short)p1[e]);
                af[e] = (short)f2bf(lrelu(v * zi));
            }
        } else {
            float4 q0 = *(const float4*)&Af32[off];
            float4 q1 = *(const float4*)&Af32[off + 4];
            af[0] = (short)f2bf(q0.x); af[1] = (short)f2bf(q0.y);
            af[2] = (short)f2bf(q0.z); af[3] = (short)f2bf(q0.w);
            af[4] = (short)f2bf(q1.x); af[5] = (short)f2bf(q1.y);
            af[6] = (short)f2bf(q1.z); af[7] = (short)f2bf(q1.w);
        }
#pragma unroll
        for (int ct = 0; ct < 4; ++ct) {
            bf16x8 bfv = *(const bf16x8*)&WTg[(size_t)(n0 + ct * 16 + colg) * K + kk + koff];
            acc[ct] = __builtin_amdgcn_mfma_f32_16x16x32_bf16(af, bfv, acc[ct], 0, 0, 0);
        }
    }

    // ---- epilogue: bias, src/dst partial dots (shfl-reduce over colg), hTf stores ----
    const int r = n0 >> 7, chalf = n0 & 127;
    const int b = m0 >> 8, jb = m0 & 255;
    float val[4][4];
    float ssum[4] = {0.f, 0.f, 0.f, 0.f}, dsum[4] = {0.f, 0.f, 0.f, 0.f};
#pragma unroll
    for (int ct = 0; ct < 4; ++ct) {
        int cg = chalf + ct * 16 + colg;
        float bv = bias[n0 + ct * 16 + colg];
        float asr = avec[r * 256 + cg];
        float ads = avec[r * 256 + 128 + cg];
#pragma unroll
        for (int reg = 0; reg < 4; ++reg) {
            float v = acc[ct][reg] + bv;
            val[ct][reg] = v;
            ssum[reg] += v * asr;
            dsum[reg] += v * ads;
        }
    }
#pragma unroll
    for (int mk = 1; mk < 16; mk <<= 1)
#pragma unroll
        for (int reg = 0; reg < 4; ++reg) {
            ssum[reg] += __shfl_xor(ssum[reg], mk);
            dsum[reg] += __shfl_xor(dsum[reg], mk);
        }
    if (colg == 0) {
        int half = (n0 >> 6) & 1;
#pragma unroll
        for (int reg = 0; reg < 4; ++reg) {
            int row = m0 + w * 16 + rquad * 4 + reg;
            srcp[half * 40960 + row * 5 + r] = ssum[reg];
            dstp[half * 40960 + row * 5 + r] = dsum[reg];
        }
    }
    // hTf direct stores: reg-quad = 4 consecutive j (8 B contiguous)
    {
        const int joct = (jb >> 3) + w * 2 + (rquad >> 1);
        const size_t tile = (size_t)((b * 5 + r) * 32 + joct) * 1024;
        const int sub = (rquad & 1) * 4;
#pragma unroll
        for (int ct = 0; ct < 4; ++ct) {
            int c = chalf + ct * 16 + colg;
            uint2 pk;
            pk.x = (unsigned)f2bf(val[ct][0]) | ((unsigned)f2bf(val[ct][1]) << 16);
            pk.y = (unsigned)f2bf(val[ct][2]) | ((unsigned)f2bf(val[ct][3]) << 16);
            *(uint2*)&hTf[tile + (size_t)c * 8 + sub] = pk;
        }
    }
}

// =======================================================================================
// k_agg: grid (2 js of 128 j, 16 i-tiles of 16, 32 b) = 1024 blocks, 256 threads = 4 waves.
// Unnormalized e = mask ? exp(lrelu(src+dst)) : 0 (bf16) in LDS (16 i x 640 k = 20 KB).
// Writes aggPb[js][row][c] (bf16) and Zpart[js][row] (fp32). ~26 KB LDS -> 6 blocks/CU.
// B fragments for MFMA steps 0-1 are prefetched into registers BEFORE the P-gen barrier
// so the VMEM latency overlaps the exp-heavy VALU phase.
// =======================================================================================
__global__ __launch_bounds__(256) void k_agg(const unsigned short* __restrict__ hTf,
                                             const float* __restrict__ srcp,
                                             const float* __restrict__ dstp,
                                             const unsigned char* __restrict__ maskp,
                                             unsigned short* __restrict__ aggPb,
                                             float* __restrict__ Zpart) {
    __shared__ unsigned short Ps[10240];          // 20 s x 64 chunks x 8 bf16 = 20 KB
    __shared__ float Ss[80], Ds2l[640], Zrow[16];
    const int t = threadIdx.x;
    const int js = blockIdx.x, itile = blockIdx.y, b = blockIdx.z;
    const int ib = b * 256 + itile * 16;
    const int w = t >> 6, lane = t & 63;
    const int colg = lane & 15, rquad = lane >> 4;
    const size_t bbase = (size_t)(b * 5) * 32 * 1024;

    if (t < 80) Ss[t] = srcp[(size_t)ib * 5 + t] + srcp[40960 + (size_t)ib * 5 + t];
    if (t >= 80 && t < 96) Zrow[t - 80] = 0.f;
    for (int idx = t; idx < 640; idx += 256) {
        int jl = idx & 127, rr = idx >> 7;
        size_t o = (size_t)(b * 256 + js * 128 + jl) * 5 + rr;
        Ds2l[rr * 128 + jl] = dstp[o] + dstp[40960 + o];
    }

    // B prefetch for s = 0,1 (independent of Ps; streams under P-gen VALU)
    bf16x8 pre[2][2];
#pragma unroll
    for (int s = 0; s < 2; ++s) {
        const int joct = js * 16 + s * 4 + rquad;            // rr = 0 for s<4
        const size_t tbase = bbase + (size_t)joct * 1024;
#pragma unroll
        for (int ct = 0; ct < 2; ++ct) {
            int c = w * 32 + ct * 16 + colg;
            pre[s][ct] = *(const bf16x8*)&hTf[tbase + (size_t)c * 8];
        }
    }
    __syncthreads();

    // P generation: 1280 chunks of 8; thread t -> chunks it*256+t (i = t&15 fixed)
    {
        const int i = t & 15;
        float esum = 0.f;
#pragma unroll
        for (int it = 0; it < 5; ++it) {
            int p = it * 256 + t;
            int lane8 = p & 63, s = p >> 6;           // s in [0,20)
            int kq = lane8 >> 4;
            int k0 = s * 32 + kq * 8;                 // k0 in [0,640)
            int rr = k0 >> 7, j0l = k0 & 127;
            uint2 mk8 = *(const uint2*)&maskp[((size_t)(ib + i) << 8) + js * 128 + j0l];
            float sv = Ss[i * 5 + rr];
            bf16x8 pv;
#pragma unroll
            for (int e = 0; e < 8; ++e) {
                unsigned mb = ((e < 4 ? (mk8.x >> (8 * e)) : (mk8.y >> (8 * (e - 4)))) >> rr) & 1u;
                float v = lrelu(sv + Ds2l[rr * 128 + j0l + e]);
                float ev = mb ? __expf(v) : 0.f;
                unsigned short q = f2bf(ev);
                pv[e] = (short)q;
                esum += __uint_as_float((unsigned)q << 16);
            }
            *(bf16x8*)&Ps[p * 8] = pv;
        }
        atomicAdd(&Zrow[i], esum);
    }
    __syncthreads();
    if (t < 16) Zpart[(size_t)js * 8192 + ib + t] = Zrow[t];

    // MFMA: wave w -> c in [w*32, w*32+32); 20 steps over (r, j-window)
    f32x4 acc[2] = {};
#pragma unroll
    for (int s = 0; s < 20; ++s) {
        bf16x8 af = *(const bf16x8*)&Ps[(s * 64 + lane) * 8];
        const int rr = s >> 2;
        const int joct = js * 16 + (s & 3) * 4 + rquad;
        const size_t tbase = bbase + (size_t)(rr * 32 + joct) * 1024;
#pragma unroll
        for (int ct = 0; ct < 2; ++ct) {
            bf16x8 bfv;
            if (s < 2) {
                bfv = pre[s][ct];
            } else {
                int c = w * 32 + ct * 16 + colg;
                bfv = *(const bf16x8*)&hTf[tbase + (size_t)c * 8];
            }
            acc[ct] = __builtin_amdgcn_mfma_f32_16x16x32_bf16(af, bfv, acc[ct], 0, 0, 0);
        }
    }
    unsigned short* op = aggPb + (size_t)js * 1048576;      // 8192*128 bf16
    const int irow = ib + rquad * 4;
#pragma unroll
    for (int ct = 0; ct < 2; ++ct) {
        int c = w * 32 + ct * 16 + colg;
#pragma unroll
        for (int reg = 0; reg < 4; ++reg)
            op[(size_t)(irow + reg) * 128 + c] = f2bf(acc[ct][reg]);
    }
}

// =======================================================================================
// k_pool: per (n-chunk of 32, b): chunk sum & max of h3 = (aggPb0+aggPb1)/Z over n.
// grid (8, 32), 256 threads. Coalesced over c.
// =======================================================================================
__global__ __launch_bounds__(256) void k_pool(const unsigned short* __restrict__ aggPb,
                                              const float* __restrict__ Zpart,
                                              float* __restrict__ poolS,
                                              float* __restrict__ poolM) {
    int nc = blockIdx.x, b = blockIdx.y;
    int t = threadIdx.x;
    int c = t & 127, sub = t >> 7;
    __shared__ float Zl[32];
    __shared__ float Sh[2][128], Mh[2][128];
    if (t < 32) {
        int rowg = b * 256 + nc * 32 + t;
        Zl[t] = 1.f / (Zpart[rowg] + Zpart[8192 + rowg]);
    }
    __syncthreads();
    float sm = 0.f, mx = -3.4e38f;
#pragma unroll
    for (int nn = 0; nn < 16; ++nn) {
        int nl = sub * 16 + nn;
        size_t o = (size_t)(b * 256 + nc * 32 + nl) * 128 + c;
        float v = (bf2f(aggPb[o]) + bf2f(aggPb[o + 1048576])) * Zl[nl];
        sm += v; mx = fmaxf(mx, v);
    }
    Sh[sub][c] = sm; Mh[sub][c] = mx;
    __syncthreads();
    if (t < 128) {
        poolS[(b * 8 + nc) * 128 + t] = Sh[0][t] + Sh[1][t];
        poolM[(b * 8 + nc) * 128 + t] = fmaxf(Mh[0][t], Mh[1][t]);
    }
}

// =======================================================================================
// k_mlp1: z1[b][o] = lrelu( z . We1T[o] + be1[o] ), z = [x | mean | max] (1280).
// grid (16 og, 32 b) = 512 blocks, 256 threads; wave computes 4 outputs (shfl-reduce).
// =======================================================================================
__global__ __launch_bounds__(256) void k_mlp1(const float* __restrict__ x,
                                              const float* __restrict__ poolS,
                                              const float* __restrict__ poolM,
                                              const float* __restrict__ We1T,
                                              const float* __restrict__ be1,
                                              float* __restrict__ z1g) {
    int og = blockIdx.x, b = blockIdx.y;
    int t = threadIdx.x;
    __shared__ float zs[1280];
    for (int i = t; i < 1024; i += 256) zs[i] = x[b * 1024 + i];
    if (t < 128) {
        float s = 0.f;
#pragma unroll
        for (int nc = 0; nc < 8; ++nc) s += poolS[(b * 8 + nc) * 128 + t];
        zs[1024 + t] = s * (1.f / 256.f);
    } else {
        int f = t - 128;
        float mx = -3.4e38f;
#pragma unroll
        for (int nc = 0; nc < 8; ++nc) mx = fmaxf(mx, poolM[(b * 8 + nc) * 128 + f]);
        zs[1152 + f] = mx;
    }
    __syncthreads();
    int w = t >> 6, lane = t & 63;
#pragma unroll
    for (int oo = 0; oo < 4; ++oo) {
        int o = og * 16 + w * 4 + oo;
        float s = 0.f;
#pragma unroll
        for (int i = 0; i < 20; ++i) {
            int k = i * 64 + lane;
            s += zs[k] * We1T[(size_t)o * 1280 + k];
        }
#pragma unroll
        for (int off = 32; off > 0; off >>= 1) s += __shfl_down(s, off);
        if (lane == 0) z1g[b * 256 + o] = lrelu(s + be1[o]);
    }
}

// ---------------- MLP layers 2+3 ----------------
__global__ __launch_bounds__(256) void k_mlp23(const float* __restrict__ z1g,
                                               const float* __restrict__ We2,
                                               const float* __restrict__ be2,
                                               const float* __restrict__ We3,
                                               const float* __restrict__ be3,
                                               float* __restrict__ out) {
    int b = blockIdx.x, t = threadIdx.x;
    __shared__ float zs[256], z2s[32];
    zs[t] = z1g[b * 256 + t];
    __syncthreads();
    if (t < 32) {
        float s2 = be2[t];
        for (int k = 0; k < 256; ++k) s2 += zs[k] * We2[k * 32 + t];
        z2s[t] = lrelu(s2);
    }
    __syncthreads();
    if (t == 0) {
        float s3 = be3[0];
#pragma unroll
        for (int k = 0; k < 32; ++k) s3 += z2s[k] * We3[k];
        out[b] = s3;
    }
}

// ---------------- workspace layout ----------------
constexpr size_t O_MASK  = 0;                                  // 2 MB
constexpr size_t O_SRCP  = 2097152;                            // 2 x 40960 floats
constexpr size_t O_DSTP  = O_SRCP + 2ull * 40960 * 4;
constexpr size_t O_AGG   = O_DSTP + 2ull * 40960 * 4;          // 2 x 8192 x 128 bf16 = 4.2 MB
constexpr size_t O_ZP    = O_AGG + 2ull * 1048576 * 2;         // 2 x 8192 floats
constexpr size_t O_HT    = O_ZP + 2ull * 8192 * 4;             // 10.5 MB
constexpr size_t O_WT1   = O_HT + 5242880ull * 2;
constexpr size_t O_WT2   = O_WT1 + 640ull * 64 * 2;
constexpr size_t O_WT3   = O_WT2 + 640ull * 128 * 2;
constexpr size_t O_WE1T  = O_WT3 + 640ull * 128 * 2;           // 1.31 MB
constexpr size_t O_POOLS = O_WE1T + 256ull * 1280 * 4;
constexpr size_t O_POOLM = O_POOLS + 32ull * 8 * 128 * 4;
constexpr size_t O_Z1    = O_POOLM + 32ull * 8 * 128 * 4;      // 32 KB

extern "C" void kernel_launch(void* const* d_in, const int* in_sizes, int n_in,
                              void* d_out, int out_size, void* d_ws, size_t ws_size,
                              hipStream_t stream) {
    const float* x       = (const float*)d_in[0];
    const float* y_atoms = (const float*)d_in[1];
    const int*   y_bonds = (const int*)d_in[2];
    const float* W1 = (const float*)d_in[3];
    const float* b1 = (const float*)d_in[4];
    const float* a1 = (const float*)d_in[5];
    const float* W2 = (const float*)d_in[6];
    const float* b2 = (const float*)d_in[7];
    const float* a2 = (const float*)d_in[8];
    const float* W3 = (const float*)d_in[9];
    const float* b3 = (const float*)d_in[10];
    const float* a3 = (const float*)d_in[11];
    const float* We1 = (const float*)d_in[12];
    const float* be1 = (const float*)d_in[13];
    const float* We2 = (const float*)d_in[14];
    const float* be2 = (const float*)d_in[15];
    const float* We3 = (const float*)d_in[16];
    const float* be3 = (const float*)d_in[17];
    float* out = (float*)d_out;

    char* ws = (char*)d_ws;
    unsigned char* maskp = (unsigned char*)(ws + O_MASK);
    float* srcp = (float*)(ws + O_SRCP);
    float* dstp = (float*)(ws + O_DSTP);
    unsigned short* aggPb = (unsigned short*)(ws + O_AGG);
    float* Zpart = (float*)(ws + O_ZP);
    unsigned short* hTf = (unsigned short*)(ws + O_HT);
    unsigned short* WT1 = (unsigned short*)(ws + O_WT1);
    unsigned short* WT2 = (unsigned short*)(ws + O_WT2);
    unsigned short* WT3 = (unsigned short*)(ws + O_WT3);
    float* We1T  = (float*)(ws + O_WE1T);
    float* poolS = (float*)(ws + O_POOLS);
    float* poolM = (float*)(ws + O_POOLM);
    float* z1g   = (float*)(ws + O_Z1);

    dim3 blk(256);

    k_prep<<<8254, blk, 0, stream>>>(W1, W2, W3, We1, y_bonds, WT1, WT2, WT3, We1T, maskp);

    // layer 1
    k_gemm_h<64, 0><<<dim3(10, 128), blk, 0, stream>>>(
        y_atoms, nullptr, nullptr, WT1, b1, a1, srcp, dstp, hTf);
    k_agg<<<dim3(2, 16, 32), blk, 0, stream>>>(hTf, srcp, dstp, maskp, aggPb, Zpart);

    // layer 2
    k_gemm_h<128, 1><<<dim3(10, 128), blk, 0, stream>>>(
        nullptr, aggPb, Zpart, WT2, b2, a2, srcp, dstp, hTf);
    k_agg<<<dim3(2, 16, 32), blk, 0, stream>>>(hTf, srcp, dstp, maskp, aggPb, Zpart);

    // layer 3
    k_gemm_h<128, 1><<<dim3(10, 128), blk, 0, stream>>>(
        nullptr, aggPb, Zpart, WT3, b3, a3, srcp, dstp, hTf);
    k_agg<<<dim3(2, 16, 32), blk, 0, stream>>>(hTf, srcp, dstp, maskp, aggPb, Zpart);

    // pool + parallel MLP head
    k_pool<<<dim3(8, 32), blk, 0, stream>>>(aggPb, Zpart, poolS, poolM);
    k_mlp1<<<dim3(16, 32), blk, 0, stream>>>(x, poolS, poolM, We1T, be1, z1g);
    k_mlp23<<<32, blk, 0, stream>>>(z1g, We2, be2, We3, be3, out);
}